// Round 2
// baseline (330.941 us; speedup 1.0000x reference)
//
#include <hip/hip_runtime.h>
#include <hip/hip_bf16.h>

// BGraphAttentionLayer: fused GAT layer, never materializes the 8192^2 attention.
// hp1 = E @ (Wh2/Z2), hp2 = E^T @ (Wh1/Z1), E = adj>0 ? exp(lrelu(s1_i+s2_j)) : 0.

#define N 8192
#define FIN 256
#define FOUT 64

typedef float f32x4 __attribute__((ext_vector_type(4)));
typedef short s16x8 __attribute__((ext_vector_type(8)));
typedef unsigned short u16;

__device__ __forceinline__ u16 f2bf(float x) {
  unsigned u = __builtin_bit_cast(unsigned, x);
  return (u16)((u + 0x7FFFu + ((u >> 16) & 1u)) >> 16);  // RTNE
}

__device__ __forceinline__ float eval_e(float adjv, float s1v, float s2v) {
  float x = s1v + s2v;
  float lr = fmaxf(x, 0.2f * x);     // leaky_relu(x, 0.2) == max(x, 0.2x)
  float e = __expf(lr);
  return adjv > 0.0f ? e : 0.0f;     // masked entries contribute exactly 0
}

// ---------------- K1: Wh1/Wh2 (transposed, f32) + s1/s2 ----------------
__global__ __launch_bounds__(256) void k_prep(
    const float* __restrict__ h1, const float* __restrict__ h2,
    const float* __restrict__ W1, const float* __restrict__ W2,
    const float* __restrict__ a,
    float* __restrict__ Wh1T, float* __restrict__ Wh2T,
    float* __restrict__ s1, float* __restrict__ s2) {
  __shared__ float hbuf[16][FIN];
  const int t = threadIdx.x;
  const int r0 = blockIdx.x * 16;
  const int f = t & 63, q = t >> 6;          // f: out col, q: row group
  const int lrow = t >> 4, lc0 = (t & 15) * 16;
  for (int mat = 0; mat < 2; ++mat) {
    const float* h = mat ? h2 : h1;
    const float* W = mat ? W2 : W1;
    float* WhT = mat ? Wh2T : Wh1T;
    float* so = mat ? s2 : s1;
    const float av = a[mat * FOUT + f];
    __syncthreads();
    const float* src = h + (size_t)(r0 + lrow) * FIN + lc0;
#pragma unroll
    for (int u = 0; u < 4; ++u)
      *(f32x4*)&hbuf[lrow][lc0 + u * 4] = *(const f32x4*)(src + u * 4);
    __syncthreads();
    float acc[4] = {0.f, 0.f, 0.f, 0.f};
    for (int k = 0; k < FIN; ++k) {
      float wv = W[k * FOUT + f];
#pragma unroll
      for (int rg = 0; rg < 4; ++rg)
        acc[rg] = fmaf(hbuf[rg * 4 + q][k], wv, acc[rg]);
    }
#pragma unroll
    for (int rg = 0; rg < 4; ++rg) {
      int r = r0 + rg * 4 + q;
      WhT[(size_t)f * N + r] = acc[rg];
      float sp = acc[rg] * av;
#pragma unroll
      for (int m = 1; m < 64; m <<= 1) sp += __shfl_xor(sp, m, 64);
      if (f == 0) so[r] = sp;
    }
  }
}

// ---------------- K2: fused row/col sums of E (one adj sweep) ----------------
// grid (8 col-stripes of 1024, 256 row-chunks of 32)
__global__ __launch_bounds__(256) void k_stats(
    const float* __restrict__ adj, const float* __restrict__ s1,
    const float* __restrict__ s2, float* __restrict__ Z1,
    float* __restrict__ Z2) {
  const int t = threadIdx.x;
  const int c0 = blockIdx.x * 1024 + t * 4;
  const int r0 = blockIdx.y * 32;
  const int wv = t >> 6, lane = t & 63;
  __shared__ float rowpart[4][32];
  const f32x4 s2v = *(const f32x4*)(s2 + c0);
  float ca0 = 0.f, ca1 = 0.f, ca2 = 0.f, ca3 = 0.f;
  for (int rb = 0; rb < 32; rb += 8) {
    f32x4 v[8];
#pragma unroll
    for (int u = 0; u < 8; ++u)
      v[u] = *(const f32x4*)(adj + (size_t)(r0 + rb + u) * N + c0);
#pragma unroll
    for (int u = 0; u < 8; ++u) {
      float s1v = s1[r0 + rb + u];
      float e0 = eval_e(v[u].x, s1v, s2v.x);
      float e1 = eval_e(v[u].y, s1v, s2v.y);
      float e2 = eval_e(v[u].z, s1v, s2v.z);
      float e3 = eval_e(v[u].w, s1v, s2v.w);
      ca0 += e0; ca1 += e1; ca2 += e2; ca3 += e3;
      float rs = (e0 + e1) + (e2 + e3);
#pragma unroll
      for (int m = 1; m < 64; m <<= 1) rs += __shfl_xor(rs, m, 64);
      if (lane == 0) rowpart[wv][rb + u] = rs;
    }
  }
  __syncthreads();
  if (t < 32) {
    float s = rowpart[0][t] + rowpart[1][t] + rowpart[2][t] + rowpart[3][t];
    atomicAdd(&Z1[r0 + t], s);
  }
  atomicAdd(&Z2[c0 + 0], ca0);
  atomicAdd(&Z2[c0 + 1], ca1);
  atomicAdd(&Z2[c0 + 2], ca2);
  atomicAdd(&Z2[c0 + 3], ca3);
}

// ---------------- K3: V{1,2}T = (Wh/Z)^T in bf16 ----------------
__global__ __launch_bounds__(256) void k_buildv(
    const float* __restrict__ Wh1T, const float* __restrict__ Wh2T,
    const float* __restrict__ Z1, const float* __restrict__ Z2,
    u16* __restrict__ V1T, u16* __restrict__ V2T) {
  const int mat = blockIdx.y;
  const float* WhT = mat ? Wh2T : Wh1T;
  const float* Z = mat ? Z2 : Z1;
  u16* VT = mat ? V2T : V1T;
  const int idx = (blockIdx.x * 256 + threadIdx.x) * 4;
  const int i = idx & (N - 1);
  f32x4 wh = *(const f32x4*)(WhT + idx);
  f32x4 z = *(const f32x4*)(Z + i);
  unsigned lo = (unsigned)f2bf(wh.x / z.x) | ((unsigned)f2bf(wh.y / z.y) << 16);
  unsigned hi = (unsigned)f2bf(wh.z / z.z) | ((unsigned)f2bf(wh.w / z.w) << 16);
  uint2 uv; uv.x = lo; uv.y = hi;
  *(uint2*)(VT + idx) = uv;
}

// ---------------- K4: main fused pass ----------------
#define BI 128
#define BJ 64
#define JC 512

// swizzled u16-index into row-major Etile[BI][BJ]; XOR touches bits 3..5 only,
// so 8-u16 (16B) runs stay contiguous for ds_read_b128.
__device__ __forceinline__ int eswz(int il, int jl) {
  return (il * BJ + jl) ^ ((il & 7) << 3);
}
// swizzled u16-index into transposed EtileT[BJ][BI]; XOR touches bits 3..6 only.
__device__ __forceinline__ int etswz(int jl, int il) {
  return (jl * BI + il) ^ ((jl & 0x1E) << 2);
}

__global__ __launch_bounds__(256, 4) void k_main(
    const float* __restrict__ adj, const float* __restrict__ s1g,
    const float* __restrict__ s2g, const u16* __restrict__ V1T,
    const u16* __restrict__ V2T, float* __restrict__ hp1,
    float* __restrict__ hp2) {
  __shared__ u16 Etile[BI * BJ];
  __shared__ u16 EtileT[BJ * BI];
  __shared__ float s1s[BI];
  const int t = threadIdx.x;
  const int w = t >> 6, lane = t & 63;
  const int l15 = lane & 15, l4 = lane >> 4;
  const int i0 = blockIdx.y * BI;
  const int j0 = blockIdx.x * JC;
  if (t < BI) s1s[t] = s1g[i0 + t];
  f32x4 acc1[2][4];
#pragma unroll
  for (int mt = 0; mt < 2; ++mt)
#pragma unroll
    for (int nt = 0; nt < 4; ++nt) acc1[mt][nt] = f32x4{0.f, 0.f, 0.f, 0.f};
  __syncthreads();

  const int cq = t & 15, rr = t >> 4;   // col-group (4 cols), row-group-of-16
  for (int js = 0; js < JC / BJ; ++js) {
    const int j0s = j0 + js * BJ;
    // phase 1: build E (row-major) AND E^T tiles in LDS.
    // Thread owns two 4x4 sub-blocks -> in-register transpose, 8B LDS writes.
    {
      const int jj = j0s + cq * 4;
      const f32x4 s2v = *(const f32x4*)(s2g + jj);
#pragma unroll
      for (int p = 0; p < 2; ++p) {
        const int il0 = (rr + p * 16) * 4;
        f32x4 av[4];
#pragma unroll
        for (int r = 0; r < 4; ++r)
          av[r] = *(const f32x4*)(adj + (size_t)(i0 + il0 + r) * N + jj);
        u16 eb[4][4];
#pragma unroll
        for (int r = 0; r < 4; ++r) {
          const float s1v = s1s[il0 + r];
          eb[r][0] = f2bf(eval_e(av[r].x, s1v, s2v.x));
          eb[r][1] = f2bf(eval_e(av[r].y, s1v, s2v.y));
          eb[r][2] = f2bf(eval_e(av[r].z, s1v, s2v.z));
          eb[r][3] = f2bf(eval_e(av[r].w, s1v, s2v.w));
        }
#pragma unroll
        for (int r = 0; r < 4; ++r) {
          uint2 val;
          val.x = (unsigned)eb[r][0] | ((unsigned)eb[r][1] << 16);
          val.y = (unsigned)eb[r][2] | ((unsigned)eb[r][3] << 16);
          *(uint2*)&Etile[eswz(il0 + r, cq * 4)] = val;
        }
#pragma unroll
        for (int c = 0; c < 4; ++c) {
          uint2 val;
          val.x = (unsigned)eb[0][c] | ((unsigned)eb[1][c] << 16);
          val.y = (unsigned)eb[2][c] | ((unsigned)eb[3][c] << 16);
          *(uint2*)&EtileT[etswz(cq * 4 + c, il0)] = val;
        }
      }
    }
    __syncthreads();
    // phase 2a: hp1 += E @ V2   (A-frags from LDS, B-frags from L2-hot V2T)
#pragma unroll
    for (int kk = 0; kk < 2; ++kk) {
      s16x8 bfr[4];
#pragma unroll
      for (int nt = 0; nt < 4; ++nt) {
        const int fr = nt * 16 + l15;
        const int jj = j0s + kk * 32 + l4 * 8;
        bfr[nt] = *(const s16x8*)(V2T + (size_t)fr * N + jj);
      }
#pragma unroll
      for (int mt = 0; mt < 2; ++mt) {
        const int il = w * 32 + mt * 16 + l15;
        const int jl = kk * 32 + l4 * 8;
        s16x8 aE = *(const s16x8*)&Etile[eswz(il, jl)];
#pragma unroll
        for (int nt = 0; nt < 4; ++nt)
          acc1[mt][nt] = __builtin_amdgcn_mfma_f32_16x16x32_bf16(
              aE, bfr[nt], acc1[mt][nt], 0, 0, 0);
      }
    }
    // phase 2b: hp2 += E^T @ V1  (A-frags from transposed LDS tile)
    {
      const int jl2 = w * 16 + l15;
      f32x4 acc2[4];
#pragma unroll
      for (int nt = 0; nt < 4; ++nt) acc2[nt] = f32x4{0.f, 0.f, 0.f, 0.f};
#pragma unroll
      for (int kk = 0; kk < 4; ++kk) {
        s16x8 aET = *(const s16x8*)&EtileT[etswz(jl2, kk * 32 + l4 * 8)];
        s16x8 bfr[4];
#pragma unroll
        for (int nt = 0; nt < 4; ++nt) {
          const int fr = nt * 16 + l15;
          const int ii = i0 + kk * 32 + l4 * 8;
          bfr[nt] = *(const s16x8*)(V1T + (size_t)fr * N + ii);
        }
#pragma unroll
        for (int nt = 0; nt < 4; ++nt)
          acc2[nt] = __builtin_amdgcn_mfma_f32_16x16x32_bf16(
              aET, bfr[nt], acc2[nt], 0, 0, 0);
      }
#pragma unroll
      for (int nt = 0; nt < 4; ++nt)
#pragma unroll
        for (int r = 0; r < 4; ++r) {
          const int jr = j0s + w * 16 + l4 * 4 + r;
          const int fc = nt * 16 + l15;
          atomicAdd(&hp2[(size_t)jr * FOUT + fc], acc2[nt][r]);
        }
    }
    __syncthreads();
  }
  // hp1 writeout (accumulated over all 8 j-steps; 16 j-chunk blocks contribute)
#pragma unroll
  for (int mt = 0; mt < 2; ++mt)
#pragma unroll
    for (int nt = 0; nt < 4; ++nt)
#pragma unroll
      for (int r = 0; r < 4; ++r) {
        const int ir = i0 + w * 32 + mt * 16 + l4 * 4 + r;
        const int fc = nt * 16 + l15;
        atomicAdd(&hp1[(size_t)ir * FOUT + fc], acc1[mt][nt][r]);
      }
}

// ---------------- K5: ELU epilogue ----------------
__global__ __launch_bounds__(256) void k_final(const float* __restrict__ hp,
                                               float* __restrict__ out) {
  const int idx = (blockIdx.x * 256 + threadIdx.x) * 4;
  f32x4 v = *(const f32x4*)(hp + idx);
  f32x4 o;
  o.x = v.x > 0.f ? v.x : expm1f(v.x);
  o.y = v.y > 0.f ? v.y : expm1f(v.y);
  o.z = v.z > 0.f ? v.z : expm1f(v.z);
  o.w = v.w > 0.f ? v.w : expm1f(v.w);
  *(f32x4*)(out + idx) = o;
}

extern "C" void kernel_launch(void* const* d_in, const int* in_sizes, int n_in,
                              void* d_out, int out_size, void* d_ws,
                              size_t ws_size, hipStream_t stream) {
  const float* h1 = (const float*)d_in[0];
  const float* h2 = (const float*)d_in[1];
  const float* adj = (const float*)d_in[2];
  const float* W1 = (const float*)d_in[3];
  const float* W2 = (const float*)d_in[4];
  const float* a = (const float*)d_in[5];

  float* ws = (float*)d_ws;
  // float-offset workspace layout (~10.2 MB total)
  float* s1 = ws + 0;
  float* s2 = ws + 8192;
  float* Z1 = ws + 16384;
  float* Z2 = ws + 24576;
  float* Wh1T = ws + 32768;              // [64][8192] f32
  float* Wh2T = ws + 557056;
  float* hp1 = ws + 1081344;             // [8192][64] f32
  float* hp2 = ws + 1605632;
  u16* V1T = (u16*)(ws + 2129920);       // [64][8192] bf16
  u16* V2T = V1T + 524288;

  hipMemsetAsync(Z1, 0, 2 * 8192 * sizeof(float), stream);          // Z1+Z2
  hipMemsetAsync(hp1, 0, 2 * (size_t)N * FOUT * sizeof(float), stream);  // hp1+hp2

  k_prep<<<512, 256, 0, stream>>>(h1, h2, W1, W2, a, Wh1T, Wh2T, s1, s2);
  k_stats<<<dim3(8, 256), 256, 0, stream>>>(adj, s1, s2, Z1, Z2);
  k_buildv<<<dim3(512, 2), 256, 0, stream>>>(Wh1T, Wh2T, Z1, Z2, V1T, V2T);
  k_main<<<dim3(N / JC, N / BI), 256, 0, stream>>>(adj, s1, s2, V1T, V2T, hp1, hp2);
  k_final<<<1024, 256, 0, stream>>>(hp1, (float*)d_out);
}

// Round 3
// 241.932 us; speedup vs baseline: 1.3679x; 1.3679x over previous
//
#include <hip/hip_runtime.h>
#include <hip/hip_bf16.h>

// BGraphAttentionLayer: fused GAT layer, never materializes the 8192^2 attention.
// hp1 = E @ (Wh2/Z2), hp2 = E^T @ (Wh1/Z1), E = adj>0 ? exp(lrelu(s1_i+s2_j)) : 0.

#define N 8192
#define FIN 256
#define FOUT 64

typedef float f32x4 __attribute__((ext_vector_type(4)));
typedef short s16x8 __attribute__((ext_vector_type(8)));
typedef unsigned short u16;

__device__ __forceinline__ u16 f2bf(float x) {
  unsigned u = __builtin_bit_cast(unsigned, x);
  return (u16)((u + 0x7FFFu + ((u >> 16) & 1u)) >> 16);  // RTNE
}
__device__ __forceinline__ u16 f2bf_t(float x) {       // truncating (cheap)
  return (u16)(__builtin_bit_cast(unsigned, x) >> 16);
}

__device__ __forceinline__ float eval_e(float adjv, float s1v, float s2v) {
  float x = s1v + s2v;
  float lr = fmaxf(x, 0.2f * x);     // leaky_relu(x, 0.2) == max(x, 0.2x)
  float e = __expf(lr);
  return adjv > 0.0f ? e : 0.0f;     // masked entries contribute exactly 0
}

// ---------------- K1: Wh1/Wh2 (transposed, f32) + s1/s2 ----------------
__global__ __launch_bounds__(256) void k_prep(
    const float* __restrict__ h1, const float* __restrict__ h2,
    const float* __restrict__ W1, const float* __restrict__ W2,
    const float* __restrict__ a,
    float* __restrict__ Wh1T, float* __restrict__ Wh2T,
    float* __restrict__ s1, float* __restrict__ s2) {
  __shared__ float hbuf[16][FIN];
  const int t = threadIdx.x;
  const int r0 = blockIdx.x * 16;
  const int f = t & 63, q = t >> 6;          // f: out col, q: row group
  const int lrow = t >> 4, lc0 = (t & 15) * 16;
  for (int mat = 0; mat < 2; ++mat) {
    const float* h = mat ? h2 : h1;
    const float* W = mat ? W2 : W1;
    float* WhT = mat ? Wh2T : Wh1T;
    float* so = mat ? s2 : s1;
    const float av = a[mat * FOUT + f];
    __syncthreads();
    const float* src = h + (size_t)(r0 + lrow) * FIN + lc0;
#pragma unroll
    for (int u = 0; u < 4; ++u)
      *(f32x4*)&hbuf[lrow][lc0 + u * 4] = *(const f32x4*)(src + u * 4);
    __syncthreads();
    float acc[4] = {0.f, 0.f, 0.f, 0.f};
    for (int k = 0; k < FIN; ++k) {
      float wv = W[k * FOUT + f];
#pragma unroll
      for (int rg = 0; rg < 4; ++rg)
        acc[rg] = fmaf(hbuf[rg * 4 + q][k], wv, acc[rg]);
    }
#pragma unroll
    for (int rg = 0; rg < 4; ++rg) {
      int r = r0 + rg * 4 + q;
      WhT[(size_t)f * N + r] = acc[rg];
      float sp = acc[rg] * av;
#pragma unroll
      for (int m = 1; m < 64; m <<= 1) sp += __shfl_xor(sp, m, 64);
      if (f == 0) so[r] = sp;
    }
  }
}

// ---------------- K2: fused row/col sums of E (one adj sweep) ----------------
__global__ __launch_bounds__(256) void k_stats(
    const float* __restrict__ adj, const float* __restrict__ s1,
    const float* __restrict__ s2, float* __restrict__ Z1,
    float* __restrict__ Z2) {
  const int t = threadIdx.x;
  const int c0 = blockIdx.x * 1024 + t * 4;
  const int r0 = blockIdx.y * 32;
  const int wv = t >> 6, lane = t & 63;
  __shared__ float rowpart[4][32];
  const f32x4 s2v = *(const f32x4*)(s2 + c0);
  float ca0 = 0.f, ca1 = 0.f, ca2 = 0.f, ca3 = 0.f;
  for (int rb = 0; rb < 32; rb += 8) {
    f32x4 v[8];
#pragma unroll
    for (int u = 0; u < 8; ++u)
      v[u] = *(const f32x4*)(adj + (size_t)(r0 + rb + u) * N + c0);
#pragma unroll
    for (int u = 0; u < 8; ++u) {
      float s1v = s1[r0 + rb + u];
      float e0 = eval_e(v[u].x, s1v, s2v.x);
      float e1 = eval_e(v[u].y, s1v, s2v.y);
      float e2 = eval_e(v[u].z, s1v, s2v.z);
      float e3 = eval_e(v[u].w, s1v, s2v.w);
      ca0 += e0; ca1 += e1; ca2 += e2; ca3 += e3;
      float rs = (e0 + e1) + (e2 + e3);
#pragma unroll
      for (int m = 1; m < 64; m <<= 1) rs += __shfl_xor(rs, m, 64);
      if (lane == 0) rowpart[wv][rb + u] = rs;
    }
  }
  __syncthreads();
  if (t < 32) {
    float s = rowpart[0][t] + rowpart[1][t] + rowpart[2][t] + rowpart[3][t];
    atomicAdd(&Z1[r0 + t], s);
  }
  atomicAdd(&Z2[c0 + 0], ca0);
  atomicAdd(&Z2[c0 + 1], ca1);
  atomicAdd(&Z2[c0 + 2], ca2);
  atomicAdd(&Z2[c0 + 3], ca3);
}

// ---------------- K3: V{1,2}T = (Wh/Z)^T in bf16 ----------------
__global__ __launch_bounds__(256) void k_buildv(
    const float* __restrict__ Wh1T, const float* __restrict__ Wh2T,
    const float* __restrict__ Z1, const float* __restrict__ Z2,
    u16* __restrict__ V1T, u16* __restrict__ V2T) {
  const int mat = blockIdx.y;
  const float* WhT = mat ? Wh2T : Wh1T;
  const float* Z = mat ? Z2 : Z1;
  u16* VT = mat ? V2T : V1T;
  const int idx = (blockIdx.x * 256 + threadIdx.x) * 4;
  const int i = idx & (N - 1);
  f32x4 wh = *(const f32x4*)(WhT + idx);
  f32x4 z = *(const f32x4*)(Z + i);
  unsigned lo = (unsigned)f2bf(wh.x / z.x) | ((unsigned)f2bf(wh.y / z.y) << 16);
  unsigned hi = (unsigned)f2bf(wh.z / z.z) | ((unsigned)f2bf(wh.w / z.w) << 16);
  uint2 uv; uv.x = lo; uv.y = hi;
  *(uint2*)(VT + idx) = uv;
}

// ---------------- K4: main fused pass ----------------
#define BI 128
#define BJ 64
#define JC 1024
#define NJS (JC / BJ)  // 16

// swizzled u16-index into row-major Etile[BI][BJ]; XOR touches bits 3..5 only,
// so 8-u16 (16B) runs stay contiguous for ds_read_b128.
__device__ __forceinline__ int eswz(int il, int jl) {
  return (il * BJ + jl) ^ ((il & 7) << 3);
}
// swizzled u16-index into transposed EtileT[BJ][BI]; XOR touches bits 3..6 only.
__device__ __forceinline__ int etswz(int jl, int il) {
  return (jl * BI + il) ^ ((jl & 0x1E) << 2);
}

__global__ __launch_bounds__(256, 2) void k_main(
    const float* __restrict__ adj, const float* __restrict__ s1g,
    const float* __restrict__ s2g, const u16* __restrict__ V1T,
    const u16* __restrict__ V2T, float* __restrict__ hp1,
    float* __restrict__ hp2) {
  __shared__ u16 Etile[BI * BJ];
  __shared__ u16 EtileT[BJ * BI];
  __shared__ float s1s[BI];
  const int t = threadIdx.x;
  const int w = t >> 6, lane = t & 63;
  const int l15 = lane & 15, l4 = lane >> 4;
  const int i0 = blockIdx.y * BI;
  const int j0 = blockIdx.x * JC;
  if (t < BI) s1s[t] = s1g[i0 + t];

  f32x4 acc1[2][4];
#pragma unroll
  for (int mt = 0; mt < 2; ++mt)
#pragma unroll
    for (int nt = 0; nt < 4; ++nt) acc1[mt][nt] = f32x4{0.f, 0.f, 0.f, 0.f};

  // hoist phase-2b B-fragments (V1T, i-indexed -> js-invariant) into regs
  s16x8 b1fr[4][4];
#pragma unroll
  for (int kk = 0; kk < 4; ++kk)
#pragma unroll
    for (int nt = 0; nt < 4; ++nt)
      b1fr[kk][nt] = *(const s16x8*)(V1T + (size_t)(nt * 16 + l15) * N + i0 +
                                     kk * 32 + l4 * 8);
  __syncthreads();

  const int cq = t & 15, rr = t >> 4;  // col-group (4 cols), row-group
  // preload js=0 adj into registers
  f32x4 A[2][4], B[2][4];
  {
    const int jj = j0 + cq * 4;
#pragma unroll
    for (int p = 0; p < 2; ++p)
#pragma unroll
      for (int r = 0; r < 4; ++r)
        A[p][r] =
            *(const f32x4*)(adj + (size_t)(i0 + (rr + p * 16) * 4 + r) * N + jj);
  }

  auto body = [&](int js, f32x4 (&cur)[2][4], f32x4 (&nxt)[2][4]) {
    const int j0s = j0 + js * BJ;
    // T14: issue next tile's adj loads first; they drain under exp+LDS+MFMA
    if (js + 1 < NJS) {
      const int jjn = j0s + BJ + cq * 4;
#pragma unroll
      for (int p = 0; p < 2; ++p)
#pragma unroll
        for (int r = 0; r < 4; ++r)
          nxt[p][r] = *(const f32x4*)(adj +
                                      (size_t)(i0 + (rr + p * 16) * 4 + r) * N +
                                      jjn);
    }
    // phase 1: build E (row-major) AND E^T tiles in LDS from cur regs.
    {
      const f32x4 s2v = *(const f32x4*)(s2g + j0s + cq * 4);
#pragma unroll
      for (int p = 0; p < 2; ++p) {
        const int il0 = (rr + p * 16) * 4;
        u16 eb[4][4];
#pragma unroll
        for (int r = 0; r < 4; ++r) {
          const float s1v = s1s[il0 + r];
          eb[r][0] = f2bf_t(eval_e(cur[p][r].x, s1v, s2v.x));
          eb[r][1] = f2bf_t(eval_e(cur[p][r].y, s1v, s2v.y));
          eb[r][2] = f2bf_t(eval_e(cur[p][r].z, s1v, s2v.z));
          eb[r][3] = f2bf_t(eval_e(cur[p][r].w, s1v, s2v.w));
        }
#pragma unroll
        for (int r = 0; r < 4; ++r) {
          uint2 val;
          val.x = (unsigned)eb[r][0] | ((unsigned)eb[r][1] << 16);
          val.y = (unsigned)eb[r][2] | ((unsigned)eb[r][3] << 16);
          *(uint2*)&Etile[eswz(il0 + r, cq * 4)] = val;
        }
#pragma unroll
        for (int c = 0; c < 4; ++c) {
          uint2 val;
          val.x = (unsigned)eb[0][c] | ((unsigned)eb[1][c] << 16);
          val.y = (unsigned)eb[2][c] | ((unsigned)eb[3][c] << 16);
          *(uint2*)&EtileT[etswz(cq * 4 + c, il0)] = val;
        }
      }
    }
    __syncthreads();
    // phase 2a: hp1 += E @ V2   (A-frags from LDS, B-frags from L2-hot V2T)
#pragma unroll
    for (int kk = 0; kk < 2; ++kk) {
      s16x8 bfr[4];
#pragma unroll
      for (int nt = 0; nt < 4; ++nt) {
        const int fr = nt * 16 + l15;
        const int jj = j0s + kk * 32 + l4 * 8;
        bfr[nt] = *(const s16x8*)(V2T + (size_t)fr * N + jj);
      }
#pragma unroll
      for (int mt = 0; mt < 2; ++mt) {
        const int il = w * 32 + mt * 16 + l15;
        const int jl = kk * 32 + l4 * 8;
        s16x8 aE = *(const s16x8*)&Etile[eswz(il, jl)];
#pragma unroll
        for (int nt = 0; nt < 4; ++nt)
          acc1[mt][nt] = __builtin_amdgcn_mfma_f32_16x16x32_bf16(
              aE, bfr[nt], acc1[mt][nt], 0, 0, 0);
      }
    }
    // phase 2b: hp2 += E^T @ V1  (A-frags from transposed LDS, B-frags hoisted)
    {
      const int jl2 = w * 16 + l15;
      f32x4 acc2[4];
#pragma unroll
      for (int nt = 0; nt < 4; ++nt) acc2[nt] = f32x4{0.f, 0.f, 0.f, 0.f};
#pragma unroll
      for (int kk = 0; kk < 4; ++kk) {
        s16x8 aET = *(const s16x8*)&EtileT[etswz(jl2, kk * 32 + l4 * 8)];
#pragma unroll
        for (int nt = 0; nt < 4; ++nt)
          acc2[nt] = __builtin_amdgcn_mfma_f32_16x16x32_bf16(
              aET, b1fr[kk][nt], acc2[nt], 0, 0, 0);
      }
#pragma unroll
      for (int nt = 0; nt < 4; ++nt)
#pragma unroll
        for (int r = 0; r < 4; ++r) {
          const int jr = j0s + w * 16 + l4 * 4 + r;
          const int fc = nt * 16 + l15;
          atomicAdd(&hp2[(size_t)jr * FOUT + fc], acc2[nt][r]);
        }
    }
    __syncthreads();
  };

  for (int js2 = 0; js2 < NJS; js2 += 2) {
    body(js2, A, B);
    body(js2 + 1, B, A);
  }

  // hp1 writeout (accumulated over all NJS j-steps; 8 j-chunk blocks contribute)
#pragma unroll
  for (int mt = 0; mt < 2; ++mt)
#pragma unroll
    for (int nt = 0; nt < 4; ++nt)
#pragma unroll
      for (int r = 0; r < 4; ++r) {
        const int ir = i0 + w * 32 + mt * 16 + l4 * 4 + r;
        const int fc = nt * 16 + l15;
        atomicAdd(&hp1[(size_t)ir * FOUT + fc], acc1[mt][nt][r]);
      }
}

// ---------------- K5: ELU epilogue ----------------
__global__ __launch_bounds__(256) void k_final(const float* __restrict__ hp,
                                               float* __restrict__ out) {
  const int idx = (blockIdx.x * 256 + threadIdx.x) * 4;
  f32x4 v = *(const f32x4*)(hp + idx);
  f32x4 o;
  o.x = v.x > 0.f ? v.x : expm1f(v.x);
  o.y = v.y > 0.f ? v.y : expm1f(v.y);
  o.z = v.z > 0.f ? v.z : expm1f(v.z);
  o.w = v.w > 0.f ? v.w : expm1f(v.w);
  *(f32x4*)(out + idx) = o;
}

extern "C" void kernel_launch(void* const* d_in, const int* in_sizes, int n_in,
                              void* d_out, int out_size, void* d_ws,
                              size_t ws_size, hipStream_t stream) {
  const float* h1 = (const float*)d_in[0];
  const float* h2 = (const float*)d_in[1];
  const float* adj = (const float*)d_in[2];
  const float* W1 = (const float*)d_in[3];
  const float* W2 = (const float*)d_in[4];
  const float* a = (const float*)d_in[5];

  float* ws = (float*)d_ws;
  // float-offset workspace layout (~10.2 MB total)
  float* s1 = ws + 0;
  float* s2 = ws + 8192;
  float* Z1 = ws + 16384;
  float* Z2 = ws + 24576;
  float* Wh1T = ws + 32768;              // [64][8192] f32
  float* Wh2T = ws + 557056;
  float* hp1 = ws + 1081344;             // [8192][64] f32
  float* hp2 = ws + 1605632;
  u16* V1T = (u16*)(ws + 2129920);       // [64][8192] bf16
  u16* V2T = V1T + 524288;

  hipMemsetAsync(Z1, 0, 2 * 8192 * sizeof(float), stream);          // Z1+Z2
  hipMemsetAsync(hp1, 0, 2 * (size_t)N * FOUT * sizeof(float), stream);  // hp1+hp2

  k_prep<<<512, 256, 0, stream>>>(h1, h2, W1, W2, a, Wh1T, Wh2T, s1, s2);
  k_stats<<<dim3(8, 256), 256, 0, stream>>>(adj, s1, s2, Z1, Z2);
  k_buildv<<<dim3(512, 2), 256, 0, stream>>>(Wh1T, Wh2T, Z1, Z2, V1T, V2T);
  k_main<<<dim3(N / JC, N / BI), 256, 0, stream>>>(adj, s1, s2, V1T, V2T, hp1, hp2);
  k_final<<<1024, 256, 0, stream>>>(hp1, (float*)d_out);
}